// Round 18
// baseline (103.300 us; speedup 1.0000x reference)
//
#include <hip/hip_runtime.h>

// Head: x[8,2048,1024] fp32 -> q,k,v = x@w{q,k,v} -> causal softmax(q k^T * sqrt(128)) @ v
// Precision: bf16x3 split-GEMM for Q/K projections and QK^T (fp32-grade scores), bf16 V/PV.
// Q/K/V stored in MFMA-fragment-major layout (64-lane x 16B frags contiguous); flash reads
// operands straight from L2 (coalesced 1KB frags). Softmax in log2 domain (log2e in wq).
// qkv uses 128x128 block / 64x64 wave tiles: 3 MFMAs per ds_read_b128 (1.5x less LDS BW).

#define NB 8
#define NT 2048
#define NE 1024
#define ND 128

typedef unsigned short U16;
typedef unsigned int U32;
typedef __attribute__((ext_vector_type(8))) short vbf8;  // 8 bf16 (4 VGPR) MFMA frag
typedef __attribute__((ext_vector_type(4))) float vf4;   // MFMA 16x16 accum

#define EXP2F(x) __builtin_amdgcn_exp2f(x)  // v_exp_f32: D = 2^S0

__device__ __forceinline__ U16 f2bf(float f) {  // RNE fp32->bf16
  U32 u = __builtin_bit_cast(U32, f);
  u += 0x7fffu + ((u >> 16) & 1u);
  return (U16)(u >> 16);
}
__device__ __forceinline__ float bf2f(U16 h) {
  U32 u = ((U32)h) << 16;
  return __builtin_bit_cast(float, u);
}
__device__ __forceinline__ void gl_lds16(const void* g, void* l) {
  __builtin_amdgcn_global_load_lds((__attribute__((address_space(1))) void*)g,
                                   (__attribute__((address_space(3))) void*)l, 16, 0, 0);
}

// ---------------- kernel 1: weight transpose + split (fold sqrt(128)*log2e into wq) ---
__global__ void wsplit_kernel(const float* __restrict__ wq, const float* __restrict__ wk,
                              const float* __restrict__ wv, U16* __restrict__ wth,
                              U16* __restrict__ wtl) {
  int id = blockIdx.x * 256 + threadIdx.x;  // [0, 384*1024)
  if (id >= 384 * 1024) return;
  int n = id >> 10, e = id & 1023;
  float v;
  if (n < 128)      v = wq[e * 128 + n] * 16.322231701033217f;  // sqrt(128)*log2(e)
  else if (n < 256) v = wk[e * 128 + (n - 128)];
  else              v = wv[e * 128 + (n - 256)];
  U16 h = f2bf(v);
  wth[id] = h;
  wtl[id] = f2bf(v - bf2f(h));
}

// ---------------- kernel 2: QKV projection, bf16x3 split GEMM ------------------------
// Block tile 128(M)x128(N), BK=64, 4 waves of 64x64. grid (128, 3):
// y 0->Q(hi/lo frag) 1->K(hi/lo frag) 2->V(frag, hh only).
// LDS [row][8 granules of 16B], granule XOR-swizzled by (row&7) on BOTH sides.
// A-tile float4 loads for step t+1 issued under compute of t (T14 async-stage split).
// Epilogues bounce C through padded LDS and emit fragment-major layouts:
//   q/k frag: [b][g=row/16][kc=d/32][lane][8]  elems = M[g*16+(l&15)][kc*32+(l>>4)*8+e]
//   v   frag: [b][df=d/16][sc=s/32][lane][8]   elems = V[sc*32+(l>>4)*8+e][df*16+(l&15)]
__global__ __launch_bounds__(256, 2) void qkv_kernel(
    const float* __restrict__ x, const U16* __restrict__ wth, const U16* __restrict__ wtl,
    U16* __restrict__ qfh, U16* __restrict__ qfl, U16* __restrict__ kfh,
    U16* __restrict__ kfl, U16* __restrict__ vf) {
  __shared__ __align__(16) char smem[67584];  // loop: Ah/Al/Bh/Bl 16KB each (64KB)
  char* Ah = smem;                            // epilogue: tlh/tll [128][132] (67.6KB)
  char* Al = smem + 16384;
  char* Bh = smem + 32768;
  char* Bl = smem + 49152;

  const int tid = threadIdx.x;
  const int w = tid >> 6, lane = tid & 63;
  const int fr = lane & 15, fq = lane >> 4;
  const int m0 = blockIdx.x * 128;
  const int nt = blockIdx.y;
  const U16* bh_src = wth + nt * (128 * 1024);
  const U16* bl_src = wtl + nt * (128 * 1024);

  const vf4 vzero = {0.f, 0.f, 0.f, 0.f};
  vf4 acc[4][4];
#pragma unroll
  for (int i = 0; i < 4; ++i)
#pragma unroll
    for (int j = 0; j < 4; ++j) acc[i][j] = vzero;

  const int wm = (w >> 1) * 64, wn = (w & 1) * 64;  // wave tile 64x64
  const int arow = tid >> 1, ah = tid & 1;          // A stage: 32-float half-row
  const float* abase = x + (size_t)(m0 + arow) * 1024 + ah * 32;

  float v[32];  // A prefetch registers (tile t+1 loaded under compute of t)
#pragma unroll
  for (int j = 0; j < 8; ++j) ((float4*)v)[j] = *(const float4*)(abase + j * 4);

  for (int k0 = 0; k0 < 1024; k0 += 64) {
    // --- async-stage B hi(/lo) [128 n][64 k], source-granule pre-swizzled ---
#pragma unroll
    for (int p = 0; p < 4; ++p) {
      const int g = p * 256 + tid;
      const int row = g >> 3, c = g & 7;
      const int sc = c ^ (row & 7);
      const int ldsb = (p * 256 + w * 64) * 16;  // wave-uniform granule base
      gl_lds16(bh_src + row * 1024 + k0 + sc * 8, Bh + ldsb);
      if (nt < 2) gl_lds16(bl_src + row * 1024 + k0 + sc * 8, Bl + ldsb);
    }
    // --- split prefetched A regs -> swizzled LDS writes (4 granules/thread) ---
    {
      const int sw = arow & 7;
#pragma unroll
      for (int j = 0; j < 4; ++j) {
        vbf8 hv, lv;
#pragma unroll
        for (int e = 0; e < 8; ++e) {
          const float f = v[j * 8 + e];
          U16 a = f2bf(f);
          hv[e] = (short)a;
          lv[e] = (short)f2bf(f - bf2f(a));
        }
        const int ag = ah * 4 + j;
        *(vbf8*)(Ah + arow * 128 + ((ag ^ sw) << 4)) = hv;
        if (nt < 2) *(vbf8*)(Al + arow * 128 + ((ag ^ sw) << 4)) = lv;
      }
    }
    __syncthreads();

    // --- issue A loads for t+1 (latency hidden under the MFMA block below) ---
    if (k0 + 64 < 1024) {
      const float* s = abase + k0 + 64;
#pragma unroll
      for (int j = 0; j < 8; ++j) ((float4*)v)[j] = *(const float4*)(s + j * 4);
    }

    if (nt < 2) {
#pragma unroll
      for (int kc = 0; kc < 2; ++kc) {
        vbf8 a_h[4], a_l[4], b_h[4], b_l[4];
#pragma unroll
        for (int i = 0; i < 4; ++i) {
          const int row = wm + i * 16 + fr;
          const int off = row * 128 + (((kc * 4 + fq) ^ (row & 7)) << 4);
          a_h[i] = *(const vbf8*)(Ah + off);
          a_l[i] = *(const vbf8*)(Al + off);
        }
#pragma unroll
        for (int j = 0; j < 4; ++j) {
          const int row = wn + j * 16 + fr;
          const int off = row * 128 + (((kc * 4 + fq) ^ (row & 7)) << 4);
          b_h[j] = *(const vbf8*)(Bh + off);
          b_l[j] = *(const vbf8*)(Bl + off);
        }
#pragma unroll
        for (int i = 0; i < 4; ++i)
#pragma unroll
          for (int j = 0; j < 4; ++j) {  // (Ah+Al)(Bh+Bl) dropping Al*Bl
            acc[i][j] = __builtin_amdgcn_mfma_f32_16x16x32_bf16(a_h[i], b_h[j], acc[i][j], 0, 0, 0);
            acc[i][j] = __builtin_amdgcn_mfma_f32_16x16x32_bf16(a_h[i], b_l[j], acc[i][j], 0, 0, 0);
            acc[i][j] = __builtin_amdgcn_mfma_f32_16x16x32_bf16(a_l[i], b_h[j], acc[i][j], 0, 0, 0);
          }
      }
    } else {  // V: hh only
#pragma unroll
      for (int kc = 0; kc < 2; ++kc) {
        vbf8 a_h[4], b_h[4];
#pragma unroll
        for (int i = 0; i < 4; ++i) {
          const int row = wm + i * 16 + fr;
          a_h[i] = *(const vbf8*)(Ah + row * 128 + (((kc * 4 + fq) ^ (row & 7)) << 4));
        }
#pragma unroll
        for (int j = 0; j < 4; ++j) {
          const int row = wn + j * 16 + fr;
          b_h[j] = *(const vbf8*)(Bh + row * 128 + (((kc * 4 + fq) ^ (row & 7)) << 4));
        }
#pragma unroll
        for (int i = 0; i < 4; ++i)
#pragma unroll
          for (int j = 0; j < 4; ++j)
            acc[i][j] = __builtin_amdgcn_mfma_f32_16x16x32_bf16(a_h[i], b_h[j], acc[i][j], 0, 0, 0);
      }
    }
    __syncthreads();
  }

  const int b = m0 >> 11;
  if (nt < 2) {  // Q or K: C -> padded LDS -> hi/lo fragment-major layout
    U16* tlh = (U16*)smem;            // [128][132]
    U16* tll = (U16*)(smem + 33792);  // [128][132]
#pragma unroll
    for (int i = 0; i < 4; ++i)
#pragma unroll
      for (int j = 0; j < 4; ++j)
#pragma unroll
        for (int r = 0; r < 4; ++r) {
          const int ml = wm + i * 16 + fq * 4 + r;   // C/D: row=(lane>>4)*4+r
          const int col = wn + j * 16 + fr;          //      col=lane&15
          const float val = acc[i][j][r];
          const U16 h = f2bf(val);
          tlh[ml * 132 + col] = h;
          tll[ml * 132 + col] = f2bf(val - bf2f(h));
        }
    __syncthreads();
    U16* dh = (nt == 0) ? qfh : kfh;
    U16* dl = (nt == 0) ? qfl : kfl;
    const int g0 = (m0 & 2047) >> 4;
#pragma unroll
    for (int p = 0; p < 8; ++p) {
      const int idx = p * 256 + tid;               // 0..2047
      const int gl = idx >> 8, kc = (idx >> 6) & 3, ln = idx & 63;
      const int row = gl * 16 + (ln & 15);
      const int colc = kc * 32 + (ln >> 4) * 8;
      const size_t o = (((size_t)b * 128 + g0 + gl) * 4 + kc) * 512 + ln * 8;
      *(vbf8*)(dh + o) = *(const vbf8*)(tlh + row * 132 + colc);
      *(vbf8*)(dl + o) = *(const vbf8*)(tll + row * 132 + colc);
    }
  } else {  // V: C -> padded LDS transpose -> fragment-major layout
    U16* tl = (U16*)smem;  // [128 d][132 s-local]
#pragma unroll
    for (int i = 0; i < 4; ++i)
#pragma unroll
      for (int j = 0; j < 4; ++j)
#pragma unroll
        for (int r = 0; r < 4; ++r) {
          const int ml = wm + i * 16 + fq * 4 + r;   // s-local 0..127
          const int col = wn + j * 16 + fr;          // d 0..127
          tl[col * 132 + ml] = f2bf(acc[i][j][r]);
        }
    __syncthreads();
    const int sc0 = (m0 & 2047) >> 5;  // 4 s-chunks per block
#pragma unroll
    for (int p = 0; p < 8; ++p) {
      const int idx = p * 256 + tid;               // 0..2047
      const int df = idx >> 8, sc = (idx >> 6) & 3, ln = idx & 63;
      const int d = df * 16 + (ln & 15);
      const int sl = sc * 32 + (ln >> 4) * 8;
      const size_t o = (((size_t)b * 8 + df) * 64 + (sc0 + sc)) * 512 + ln * 8;
      *(vbf8*)(vf + o) = *(const vbf8*)(tl + d * 132 + sl);
    }
  }
}

// ---------------- kernel 3: causal flash attention, SBLK=256 frag streaming ----------
// grid 1024 = 8 b x 128 q-groups of 16 rows; block 256 thr = 4 waves, wave sq=0..3
// owns the sq-quarter (64 s-cols = 4 frags) of each 256-wide s-tile. K/V frags read
// directly from L2 (coalesced 1KB), zero staging, zero in-loop barriers. Softmax in
// log2 domain; O-rescale skipped (exact) when no row max grows. PV in two V-chunks
// reusing ONE vreg[8] (saves 32 live regs on the unified VGPR+AGPR file). 4-way merge
// at end. g mapping: heavy-desc then light-asc (LPT). min-waves 3 ((256,4) spills, r13).
__global__ __launch_bounds__(256, 3) void flash_kernel(
    const U16* __restrict__ qfh, const U16* __restrict__ qfl,
    const U16* __restrict__ kfh, const U16* __restrict__ kfl,
    const U16* __restrict__ vf, float* __restrict__ out) {
  __shared__ __align__(16) char smem[25088];
  // loop phase:  per-wave P buffer [16][72] U16 at smem + w*2304 (9216 B total)
  // merge phase: O_d [3][16][128] f32 (24576) | m_s [4][16] | l_s [4][16]

  const int tid = threadIdx.x;
  const int w = tid >> 6, lane = tid & 63;
  const int fr = lane & 15, fq = lane >> 4;
  const int sq = w;
  const int bid = blockIdx.x;
  const int bb = bid & 7;            // batch -> XCD round-robin locality
  const int jj = bid >> 3;           // 0..127
  const int g = (jj < 64) ? (127 - jj) : (jj - 64);  // LPT: heavy first, light backfill
  const int q0g = g * 16;

  // hoisted Q A-frags (coalesced 1KB frag reads)
  vbf8 q_h[4], q_l[4];
  {
    const U16* qb = qfh + ((size_t)bb * 128 + g) * 2048 + lane * 8;
    const U16* qlb = qfl + ((size_t)bb * 128 + g) * 2048 + lane * 8;
#pragma unroll
    for (int kc = 0; kc < 4; ++kc) {
      q_h[kc] = *(const vbf8*)(qb + kc * 512);
      q_l[kc] = *(const vbf8*)(qlb + kc * 512);
    }
  }

  // K frags: [b][sfi=s/16][kc][512]; wave's frags sfi = T*16 + sq*4 + sf
  const U16* khp = kfh + (size_t)bb * 262144 + (size_t)(sq * 4) * 2048 + lane * 8;
  const U16* klp = kfl + (size_t)bb * 262144 + (size_t)(sq * 4) * 2048 + lane * 8;
  // V frags: [b][df][sc=s/32][512]; wave's chunks sc = T*8 + sq*2 + c
  const U16* vfp = vf + (size_t)bb * 262144 + (size_t)(sq * 2) * 512 + lane * 8;
  U16* pw = (U16*)(smem + w * 2304);  // [16][72]

  const vf4 vzero = {0.f, 0.f, 0.f, 0.f};
  vf4 oacc[8];
#pragma unroll
  for (int i = 0; i < 8; ++i) oacc[i] = vzero;
  float m_r[4], l_r[4];
#pragma unroll
  for (int r = 0; r < 4; ++r) { m_r[r] = -__builtin_inff(); l_r[r] = 0.f; }

  const int lim = q0g + 15 - sq * 64;          // wave skips tiles fully past diagonal
  const int ntw = (lim >= 0) ? ((lim >> 8) + 1) : 0;

  for (int T = 0; T < ntw; ++T) {
    // S = Q K^T (bf16x3): 4 s-frags x 4 kc x 3 = 48 MFMAs, K frags straight from L2
    vf4 sacc[4] = {vzero, vzero, vzero, vzero};
    __builtin_amdgcn_s_setprio(1);
#pragma unroll
    for (int sf = 0; sf < 4; ++sf) {
#pragma unroll
      for (int kc = 0; kc < 4; ++kc) {
        const vbf8 kh_r = *(const vbf8*)(khp + sf * 2048 + kc * 512);
        const vbf8 kl_r = *(const vbf8*)(klp + sf * 2048 + kc * 512);
        sacc[sf] = __builtin_amdgcn_mfma_f32_16x16x32_bf16(q_h[kc], kh_r, sacc[sf], 0, 0, 0);
        sacc[sf] = __builtin_amdgcn_mfma_f32_16x16x32_bf16(q_h[kc], kl_r, sacc[sf], 0, 0, 0);
        sacc[sf] = __builtin_amdgcn_mfma_f32_16x16x32_bf16(q_l[kc], kh_r, sacc[sf], 0, 0, 0);
      }
    }
    __builtin_amdgcn_s_setprio(0);

    if (T == ntw - 1) {  // causal mask (each wave's last tile is its only partial one)
#pragma unroll
      for (int sf = 0; sf < 4; ++sf) {
        const int s_g = T * 256 + sq * 64 + sf * 16 + fr;
#pragma unroll
        for (int r = 0; r < 4; ++r)
          if (s_g > q0g + fq * 4 + r) sacc[sf][r] = -__builtin_inff();
      }
    }

    // online softmax (log2 domain) over the wave's 64 s-cols (16-lane fr groups)
    float tmax[4];
#pragma unroll
    for (int r = 0; r < 4; ++r)
      tmax[r] = fmaxf(fmaxf(sacc[0][r], sacc[1][r]), fmaxf(sacc[2][r], sacc[3][r]));
#pragma unroll
    for (int off = 1; off < 16; off <<= 1)
#pragma unroll
      for (int r = 0; r < 4; ++r) tmax[r] = fmaxf(tmax[r], __shfl_xor(tmax[r], off, 64));

    // V chunk-A loads (8) issued here; hidden under exp/psum/P-LDS below
    vbf8 vreg[8];
#pragma unroll
    for (int df = 0; df < 8; ++df) vreg[df] = *(const vbf8*)(vfp + df * 32768);

    bool need = false;
    float mne[4];
#pragma unroll
    for (int r = 0; r < 4; ++r) {
      need |= (tmax[r] > m_r[r]);
      const float mn = fmaxf(m_r[r], tmax[r]);
      mne[r] = (mn == -__builtin_inff()) ? 0.f : mn;  // fully-masked guard
    }
    if (__any(need)) {  // rescale only when some row's max grew (exact)
#pragma unroll
      for (int r = 0; r < 4; ++r) {
        const float alpha = EXP2F(m_r[r] - mne[r]);  // m_r=-inf -> 0
        l_r[r] *= alpha;
        m_r[r] = fmaxf(m_r[r], tmax[r]);
#pragma unroll
        for (int i = 0; i < 8; ++i) oacc[i][r] *= alpha;
      }
    }

    float psum[4];
    U16 pb[4][4];
#pragma unroll
    for (int sf = 0; sf < 4; ++sf)
#pragma unroll
      for (int r = 0; r < 4; ++r) {
        const float pv = EXP2F(sacc[sf][r] - mne[r]);
        psum[r] = (sf == 0) ? pv : (psum[r] + pv);
        pb[sf][r] = f2bf(pv);
      }
#pragma unroll
    for (int off = 1; off < 16; off <<= 1)
#pragma unroll
      for (int r = 0; r < 4; ++r) psum[r] += __shfl_xor(psum[r], off, 64);
#pragma unroll
    for (int r = 0; r < 4; ++r) l_r[r] += psum[r];

    // P (C-layout) -> wave-private LDS -> two A-frags (16x64 tile)
#pragma unroll
    for (int sf = 0; sf < 4; ++sf)
#pragma unroll
      for (int r = 0; r < 4; ++r) pw[(fq * 4 + r) * 72 + sf * 16 + fr] = pb[sf][r];
    asm volatile("s_waitcnt lgkmcnt(0)" ::: "memory");
    const vbf8 pf0 = *(const vbf8*)(pw + fr * 72 + fq * 8);
    const vbf8 pf1 = *(const vbf8*)(pw + fr * 72 + 32 + fq * 8);

    // PV chunk A: 8 MFMAs from prefetched V regs
    __builtin_amdgcn_s_setprio(1);
#pragma unroll
    for (int df = 0; df < 8; ++df)
      oacc[df] = __builtin_amdgcn_mfma_f32_16x16x32_bf16(pf0, vreg[df], oacc[df], 0, 0, 0);
    __builtin_amdgcn_s_setprio(0);
    __builtin_amdgcn_sched_barrier(0);  // keep chunk-B loads below (reg reuse of vreg)

    // PV chunk B: reload vreg with the second 32-s chunk, 8 MFMAs
#pragma unroll
    for (int df = 0; df < 8; ++df) vreg[df] = *(const vbf8*)(vfp + df * 32768 + 512);
    __builtin_amdgcn_s_setprio(1);
#pragma unroll
    for (int df = 0; df < 8; ++df)
      oacc[df] = __builtin_amdgcn_mfma_f32_16x16x32_bf16(pf1, vreg[df], oacc[df], 0, 0, 0);
    __builtin_amdgcn_s_setprio(0);

    khp += 32768; klp += 32768; vfp += 4096;  // next 256-wide tile
  }

  // ---- 4-way s-quarter merge (only barriers in the kernel) ----
  __syncthreads();
  float* O_d = (float*)smem;                 // [3][16][128]
  float* m_s = (float*)(smem + 24576);       // [4][16]
  float* l_s = (float*)(smem + 24832);       // [4][16]
  if (sq > 0) {
#pragma unroll
    for (int i = 0; i < 8; ++i)
#pragma unroll
      for (int r = 0; r < 4; ++r)
        O_d[((sq - 1) * 16 + fq * 4 + r) * 128 + i * 16 + fr] = oacc[i][r];
  }
  if (fr == 0) {
#pragma unroll
    for (int r = 0; r < 4; ++r) {
      m_s[sq * 16 + fq * 4 + r] = m_r[r];
      l_s[sq * 16 + fq * 4 + r] = l_r[r];
    }
  }
  __syncthreads();
  if (sq == 0) {
#pragma unroll
    for (int r = 0; r < 4; ++r) {
      const int row = fq * 4 + r;
      float mv[4];
      float M = -__builtin_inff();
#pragma unroll
      for (int p = 0; p < 4; ++p) {
        mv[p] = m_s[p * 16 + row];
        M = fmaxf(M, mv[p]);
      }
      float wgt[4], denom = 0.f;
#pragma unroll
      for (int p = 0; p < 4; ++p) {
        wgt[p] = EXP2F(mv[p] - M);             // -inf (idle/masked quarter) -> 0
        denom += wgt[p] * l_s[p * 16 + row];
      }
      const float inv = 1.f / denom;           // sq0 always has the diagonal -> denom>0
#pragma unroll
      for (int i = 0; i < 8; ++i) {
        float o = wgt[0] * oacc[i][r];
#pragma unroll
        for (int p = 1; p < 4; ++p)
          o += wgt[p] * O_d[((p - 1) * 16 + row) * 128 + i * 16 + fr];
        out[(size_t)(bb * 2048 + q0g + row) * 128 + i * 16 + fr] = o * inv;
      }
    }
  }
}

// ---------------- host ----------------------------------------------------------------
extern "C" void kernel_launch(void* const* d_in, const int* in_sizes, int n_in, void* d_out,
                              int out_size, void* d_ws, size_t ws_size, hipStream_t stream) {
  const float* x = (const float*)d_in[0];
  const float* wq = (const float*)d_in[1];
  const float* wk = (const float*)d_in[2];
  const float* wv = (const float*)d_in[3];
  char* ws = (char*)d_ws;
  U16* wth = (U16*)(ws);              // 768 KB
  U16* wtl = (U16*)(ws + 786432);     // 768 KB
  U16* qfh = (U16*)(ws + 1572864);    // 4 MiB each below (fragment-major)
  U16* qfl = (U16*)(ws + 5767168);
  U16* kfh = (U16*)(ws + 9961472);
  U16* kfl = (U16*)(ws + 14155776);
  U16* vfr = (U16*)(ws + 18350080);
  float* out = (float*)d_out;

  wsplit_kernel<<<dim3(1536), dim3(256), 0, stream>>>(wq, wk, wv, wth, wtl);
  qkv_kernel<<<dim3(128, 3), dim3(256), 0, stream>>>(x, wth, wtl, qfh, qfl, kfh, kfl, vfr);
  flash_kernel<<<dim3(1024), dim3(256), 0, stream>>>(qfh, qfl, kfh, kfl, vfr, out);
}

// Round 19
// 92.029 us; speedup vs baseline: 1.1225x; 1.1225x over previous
//
#include <hip/hip_runtime.h>

// Head: x[8,2048,1024] fp32 -> q,k,v = x@w{q,k,v} -> causal softmax(q k^T * sqrt(128)) @ v
// Precision: bf16x3 split-GEMM for Q/K projections and QK^T (fp32-grade scores), bf16 V/PV.
// Q/K/V stored in MFMA-fragment-major layout (64-lane x 16B frags contiguous); flash reads
// operands straight from L2 (coalesced 1KB frags). Softmax in log2 domain (log2e in wq).
// Flash PV runs in two V-chunks reusing one vreg[8] (32 fewer live regs -> 3 waves/SIMD).

#define NB 8
#define NT 2048
#define NE 1024
#define ND 128

typedef unsigned short U16;
typedef unsigned int U32;
typedef __attribute__((ext_vector_type(8))) short vbf8;  // 8 bf16 (4 VGPR) MFMA frag
typedef __attribute__((ext_vector_type(4))) float vf4;   // MFMA 16x16 accum

#define EXP2F(x) __builtin_amdgcn_exp2f(x)  // v_exp_f32: D = 2^S0

__device__ __forceinline__ U16 f2bf(float f) {  // RNE fp32->bf16
  U32 u = __builtin_bit_cast(U32, f);
  u += 0x7fffu + ((u >> 16) & 1u);
  return (U16)(u >> 16);
}
__device__ __forceinline__ float bf2f(U16 h) {
  U32 u = ((U32)h) << 16;
  return __builtin_bit_cast(float, u);
}
__device__ __forceinline__ void gl_lds16(const void* g, void* l) {
  __builtin_amdgcn_global_load_lds((__attribute__((address_space(1))) void*)g,
                                   (__attribute__((address_space(3))) void*)l, 16, 0, 0);
}

// ---------------- kernel 1: weight transpose + split (fold sqrt(128)*log2e into wq) ---
__global__ void wsplit_kernel(const float* __restrict__ wq, const float* __restrict__ wk,
                              const float* __restrict__ wv, U16* __restrict__ wth,
                              U16* __restrict__ wtl) {
  int id = blockIdx.x * 256 + threadIdx.x;  // [0, 384*1024)
  if (id >= 384 * 1024) return;
  int n = id >> 10, e = id & 1023;
  float v;
  if (n < 128)      v = wq[e * 128 + n] * 16.322231701033217f;  // sqrt(128)*log2(e)
  else if (n < 256) v = wk[e * 128 + (n - 128)];
  else              v = wv[e * 128 + (n - 256)];
  U16 h = f2bf(v);
  wth[id] = h;
  wtl[id] = f2bf(v - bf2f(h));
}

// ---------------- kernel 2: QKV projection, bf16x3 split GEMM ------------------------
// Tile 64(M)x128(N), BK=64. grid (256, 3): y 0->Q(hi/lo frag) 1->K(hi/lo frag) 2->V(frag).
// LDS [row][8 granules of 16B], granule XOR-swizzled by (row&7) on BOTH sides.
// A-tile float4 loads for step t+1 issued BEFORE the barrier (overlap barrier wait).
__global__ __launch_bounds__(256, 3) void qkv_kernel(
    const float* __restrict__ x, const U16* __restrict__ wth, const U16* __restrict__ wtl,
    U16* __restrict__ qfh, U16* __restrict__ qfl, U16* __restrict__ kfh,
    U16* __restrict__ kfl, U16* __restrict__ vf) {
  __shared__ __align__(16) char smem[49152];  // Ah/Al 8KB each, Bh/Bl 16KB each
  char* Ah = smem;
  char* Al = smem + 8192;
  char* Bh = smem + 16384;
  char* Bl = smem + 32768;

  const int tid = threadIdx.x;
  const int w = tid >> 6, lane = tid & 63;
  const int fr = lane & 15, fq = lane >> 4;
  const int m0 = blockIdx.x * 64;
  const int nt = blockIdx.y;
  const U16* bh_src = wth + nt * (128 * 1024);
  const U16* bl_src = wtl + nt * (128 * 1024);

  const vf4 vzero = {0.f, 0.f, 0.f, 0.f};
  vf4 acc[2][4];
#pragma unroll
  for (int i = 0; i < 2; ++i)
#pragma unroll
    for (int j = 0; j < 4; ++j) acc[i][j] = vzero;

  const int wm = (w >> 1) * 32, wn = (w & 1) * 64;  // wave tile 32x64
  const int arow = tid >> 2, ag = tid & 3;          // A stage: 2 granules (ag, ag+4)
  const float* abase = x + (size_t)(m0 + arow) * 1024 + ag * 8;

  float v0[8], v1[8];  // A prefetch registers (tile t+1 loaded under compute of t)
  {
    const float* s = abase;
    ((float4*)v0)[0] = *(const float4*)(s);
    ((float4*)v0)[1] = *(const float4*)(s + 4);
    ((float4*)v1)[0] = *(const float4*)(s + 32);
    ((float4*)v1)[1] = *(const float4*)(s + 36);
  }

  for (int k0 = 0; k0 < 1024; k0 += 64) {
    // --- async-stage B hi(/lo) [128 n][64 k], source-granule pre-swizzled ---
#pragma unroll
    for (int p = 0; p < 4; ++p) {
      const int g = p * 256 + tid;
      const int row = g >> 3, c = g & 7;
      const int sc = c ^ (row & 7);
      const int ldsb = (p * 256 + w * 64) * 16;  // wave-uniform granule base
      gl_lds16(bh_src + row * 1024 + k0 + sc * 8, Bh + ldsb);
      if (nt < 2) gl_lds16(bl_src + row * 1024 + k0 + sc * 8, Bl + ldsb);
    }
    // --- split prefetched A regs -> swizzled LDS writes ---
    {
      vbf8 h0, l0, h1, l1;
#pragma unroll
      for (int i = 0; i < 8; ++i) {
        U16 a = f2bf(v0[i]);
        h0[i] = (short)a; l0[i] = (short)f2bf(v0[i] - bf2f(a));
        U16 b = f2bf(v1[i]);
        h1[i] = (short)b; l1[i] = (short)f2bf(v1[i] - bf2f(b));
      }
      const int sw = arow & 7;
      *(vbf8*)(Ah + arow * 128 + ((ag ^ sw) << 4))       = h0;
      *(vbf8*)(Ah + arow * 128 + (((ag + 4) ^ sw) << 4)) = h1;
      if (nt < 2) {
        *(vbf8*)(Al + arow * 128 + ((ag ^ sw) << 4))       = l0;
        *(vbf8*)(Al + arow * 128 + (((ag + 4) ^ sw) << 4)) = l1;
      }
    }

    // --- issue A loads for t+1 BEFORE the barrier (regs already consumed above) ---
    if (k0 + 64 < 1024) {
      const float* s = abase + k0 + 64;
      ((float4*)v0)[0] = *(const float4*)(s);
      ((float4*)v0)[1] = *(const float4*)(s + 4);
      ((float4*)v1)[0] = *(const float4*)(s + 32);
      ((float4*)v1)[1] = *(const float4*)(s + 36);
    }
    __syncthreads();

    if (nt < 2) {
#pragma unroll
      for (int kc = 0; kc < 2; ++kc) {
        vbf8 a_h[2], a_l[2], b_h[4], b_l[4];
#pragma unroll
        for (int i = 0; i < 2; ++i) {
          const int row = wm + i * 16 + fr;
          const int off = row * 128 + (((kc * 4 + fq) ^ (row & 7)) << 4);
          a_h[i] = *(const vbf8*)(Ah + off);
          a_l[i] = *(const vbf8*)(Al + off);
        }
#pragma unroll
        for (int j = 0; j < 4; ++j) {
          const int row = wn + j * 16 + fr;
          const int off = row * 128 + (((kc * 4 + fq) ^ (row & 7)) << 4);
          b_h[j] = *(const vbf8*)(Bh + off);
          b_l[j] = *(const vbf8*)(Bl + off);
        }
#pragma unroll
        for (int i = 0; i < 2; ++i)
#pragma unroll
          for (int j = 0; j < 4; ++j) {  // (Ah+Al)(Bh+Bl) dropping Al*Bl
            acc[i][j] = __builtin_amdgcn_mfma_f32_16x16x32_bf16(a_h[i], b_h[j], acc[i][j], 0, 0, 0);
            acc[i][j] = __builtin_amdgcn_mfma_f32_16x16x32_bf16(a_h[i], b_l[j], acc[i][j], 0, 0, 0);
            acc[i][j] = __builtin_amdgcn_mfma_f32_16x16x32_bf16(a_l[i], b_h[j], acc[i][j], 0, 0, 0);
          }
      }
    } else {  // V: hh only
#pragma unroll
      for (int kc = 0; kc < 2; ++kc) {
        vbf8 a_h[2], b_h[4];
#pragma unroll
        for (int i = 0; i < 2; ++i) {
          const int row = wm + i * 16 + fr;
          a_h[i] = *(const vbf8*)(Ah + row * 128 + (((kc * 4 + fq) ^ (row & 7)) << 4));
        }
#pragma unroll
        for (int j = 0; j < 4; ++j) {
          const int row = wn + j * 16 + fr;
          b_h[j] = *(const vbf8*)(Bh + row * 128 + (((kc * 4 + fq) ^ (row & 7)) << 4));
        }
#pragma unroll
        for (int i = 0; i < 2; ++i)
#pragma unroll
          for (int j = 0; j < 4; ++j)
            acc[i][j] = __builtin_amdgcn_mfma_f32_16x16x32_bf16(a_h[i], b_h[j], acc[i][j], 0, 0, 0);
      }
    }
    __syncthreads();
  }

  const int b = m0 >> 11;
  if (nt < 2) {  // Q or K: C -> padded LDS -> hi/lo fragment-major layout
    U16* tlh = (U16*)smem;            // [64][132]
    U16* tll = (U16*)(smem + 16896);  // [64][132]
#pragma unroll
    for (int i = 0; i < 2; ++i)
#pragma unroll
      for (int j = 0; j < 4; ++j)
#pragma unroll
        for (int r = 0; r < 4; ++r) {
          const int ml = wm + i * 16 + fq * 4 + r;   // C/D: row=(lane>>4)*4+r
          const int col = wn + j * 16 + fr;          //      col=lane&15
          const float val = acc[i][j][r];
          const U16 h = f2bf(val);
          tlh[ml * 132 + col] = h;
          tll[ml * 132 + col] = f2bf(val - bf2f(h));
        }
    __syncthreads();
    U16* dh = (nt == 0) ? qfh : kfh;
    U16* dl = (nt == 0) ? qfl : kfl;
    const int g0 = (m0 & 2047) >> 4;
#pragma unroll
    for (int p = 0; p < 4; ++p) {
      const int idx = p * 256 + tid;               // 0..1023
      const int gl = idx >> 8, kc = (idx >> 6) & 3, ln = idx & 63;
      const int row = gl * 16 + (ln & 15);
      const int colc = kc * 32 + (ln >> 4) * 8;
      const size_t o = (((size_t)b * 128 + g0 + gl) * 4 + kc) * 512 + ln * 8;
      *(vbf8*)(dh + o) = *(const vbf8*)(tlh + row * 132 + colc);
      *(vbf8*)(dl + o) = *(const vbf8*)(tll + row * 132 + colc);
    }
  } else {  // V: C -> padded LDS transpose -> fragment-major layout
    U16* tl = (U16*)smem;  // [128 d][68 s-local]
#pragma unroll
    for (int i = 0; i < 2; ++i)
#pragma unroll
      for (int j = 0; j < 4; ++j)
#pragma unroll
        for (int r = 0; r < 4; ++r) {
          const int ml = wm + i * 16 + fq * 4 + r;
          const int col = wn + j * 16 + fr;
          tl[col * 68 + ml] = f2bf(acc[i][j][r]);
        }
    __syncthreads();
    const int sc0 = (m0 & 2047) >> 5;  // 2 s-chunks per block
#pragma unroll
    for (int p = 0; p < 4; ++p) {
      const int idx = p * 256 + tid;               // 0..1023
      const int df = idx >> 7, sc = (idx >> 6) & 1, ln = idx & 63;
      const int d = df * 16 + (ln & 15);
      const int sl = sc * 32 + (ln >> 4) * 8;
      const size_t o = (((size_t)b * 8 + df) * 64 + (sc0 + sc)) * 512 + ln * 8;
      *(vbf8*)(vf + o) = *(const vbf8*)(tl + d * 68 + sl);
    }
  }
}

// ---------------- kernel 3: causal flash attention, SBLK=256 frag streaming ----------
// grid 1024 = 8 b x 128 q-groups of 16 rows; block 256 thr = 4 waves, wave sq=0..3
// owns the sq-quarter (64 s-cols = 4 frags) of each 256-wide s-tile. K/V frags read
// directly from L2 (coalesced 1KB), zero staging, zero in-loop barriers. Softmax in
// log2 domain; O-rescale skipped (exact) when no row max grows. PV in two V-chunks
// reusing ONE vreg[8] (saves 32 live regs on the unified VGPR+AGPR file). 4-way merge
// at end. g mapping: heavy-desc then light-asc (LPT). min-waves 3 ((256,4) spills, r13).
__global__ __launch_bounds__(256, 3) void flash_kernel(
    const U16* __restrict__ qfh, const U16* __restrict__ qfl,
    const U16* __restrict__ kfh, const U16* __restrict__ kfl,
    const U16* __restrict__ vf, float* __restrict__ out) {
  __shared__ __align__(16) char smem[25088];
  // loop phase:  per-wave P buffer [16][72] U16 at smem + w*2304 (9216 B total)
  // merge phase: O_d [3][16][128] f32 (24576) | m_s [4][16] | l_s [4][16]

  const int tid = threadIdx.x;
  const int w = tid >> 6, lane = tid & 63;
  const int fr = lane & 15, fq = lane >> 4;
  const int sq = w;
  const int bid = blockIdx.x;
  const int bb = bid & 7;            // batch -> XCD round-robin locality
  const int jj = bid >> 3;           // 0..127
  const int g = (jj < 64) ? (127 - jj) : (jj - 64);  // LPT: heavy first, light backfill
  const int q0g = g * 16;

  // hoisted Q A-frags (coalesced 1KB frag reads)
  vbf8 q_h[4], q_l[4];
  {
    const U16* qb = qfh + ((size_t)bb * 128 + g) * 2048 + lane * 8;
    const U16* qlb = qfl + ((size_t)bb * 128 + g) * 2048 + lane * 8;
#pragma unroll
    for (int kc = 0; kc < 4; ++kc) {
      q_h[kc] = *(const vbf8*)(qb + kc * 512);
      q_l[kc] = *(const vbf8*)(qlb + kc * 512);
    }
  }

  // K frags: [b][sfi=s/16][kc][512]; wave's frags sfi = T*16 + sq*4 + sf
  const U16* khp = kfh + (size_t)bb * 262144 + (size_t)(sq * 4) * 2048 + lane * 8;
  const U16* klp = kfl + (size_t)bb * 262144 + (size_t)(sq * 4) * 2048 + lane * 8;
  // V frags: [b][df][sc=s/32][512]; wave's chunks sc = T*8 + sq*2 + c
  const U16* vfp = vf + (size_t)bb * 262144 + (size_t)(sq * 2) * 512 + lane * 8;
  U16* pw = (U16*)(smem + w * 2304);  // [16][72]

  const vf4 vzero = {0.f, 0.f, 0.f, 0.f};
  vf4 oacc[8];
#pragma unroll
  for (int i = 0; i < 8; ++i) oacc[i] = vzero;
  float m_r[4], l_r[4];
#pragma unroll
  for (int r = 0; r < 4; ++r) { m_r[r] = -__builtin_inff(); l_r[r] = 0.f; }

  const int lim = q0g + 15 - sq * 64;          // wave skips tiles fully past diagonal
  const int ntw = (lim >= 0) ? ((lim >> 8) + 1) : 0;

  for (int T = 0; T < ntw; ++T) {
    // S = Q K^T (bf16x3): 4 s-frags x 4 kc x 3 = 48 MFMAs, K frags straight from L2
    vf4 sacc[4] = {vzero, vzero, vzero, vzero};
    __builtin_amdgcn_s_setprio(1);
#pragma unroll
    for (int sf = 0; sf < 4; ++sf) {
#pragma unroll
      for (int kc = 0; kc < 4; ++kc) {
        const vbf8 kh_r = *(const vbf8*)(khp + sf * 2048 + kc * 512);
        const vbf8 kl_r = *(const vbf8*)(klp + sf * 2048 + kc * 512);
        sacc[sf] = __builtin_amdgcn_mfma_f32_16x16x32_bf16(q_h[kc], kh_r, sacc[sf], 0, 0, 0);
        sacc[sf] = __builtin_amdgcn_mfma_f32_16x16x32_bf16(q_h[kc], kl_r, sacc[sf], 0, 0, 0);
        sacc[sf] = __builtin_amdgcn_mfma_f32_16x16x32_bf16(q_l[kc], kh_r, sacc[sf], 0, 0, 0);
      }
    }
    __builtin_amdgcn_s_setprio(0);

    if (T == ntw - 1) {  // causal mask (each wave's last tile is its only partial one)
#pragma unroll
      for (int sf = 0; sf < 4; ++sf) {
        const int s_g = T * 256 + sq * 64 + sf * 16 + fr;
#pragma unroll
        for (int r = 0; r < 4; ++r)
          if (s_g > q0g + fq * 4 + r) sacc[sf][r] = -__builtin_inff();
      }
    }

    // online softmax (log2 domain) over the wave's 64 s-cols (16-lane fr groups)
    float tmax[4];
#pragma unroll
    for (int r = 0; r < 4; ++r)
      tmax[r] = fmaxf(fmaxf(sacc[0][r], sacc[1][r]), fmaxf(sacc[2][r], sacc[3][r]));
#pragma unroll
    for (int off = 1; off < 16; off <<= 1)
#pragma unroll
      for (int r = 0; r < 4; ++r) tmax[r] = fmaxf(tmax[r], __shfl_xor(tmax[r], off, 64));

    // V chunk-A loads (8) issued here; hidden under exp/psum/P-LDS below
    vbf8 vreg[8];
#pragma unroll
    for (int df = 0; df < 8; ++df) vreg[df] = *(const vbf8*)(vfp + df * 32768);

    bool need = false;
    float mne[4];
#pragma unroll
    for (int r = 0; r < 4; ++r) {
      need |= (tmax[r] > m_r[r]);
      const float mn = fmaxf(m_r[r], tmax[r]);
      mne[r] = (mn == -__builtin_inff()) ? 0.f : mn;  // fully-masked guard
    }
    if (__any(need)) {  // rescale only when some row's max grew (exact)
#pragma unroll
      for (int r = 0; r < 4; ++r) {
        const float alpha = EXP2F(m_r[r] - mne[r]);  // m_r=-inf -> 0
        l_r[r] *= alpha;
        m_r[r] = fmaxf(m_r[r], tmax[r]);
#pragma unroll
        for (int i = 0; i < 8; ++i) oacc[i][r] *= alpha;
      }
    }

    float psum[4];
    U16 pb[4][4];
#pragma unroll
    for (int sf = 0; sf < 4; ++sf)
#pragma unroll
      for (int r = 0; r < 4; ++r) {
        const float pv = EXP2F(sacc[sf][r] - mne[r]);
        psum[r] = (sf == 0) ? pv : (psum[r] + pv);
        pb[sf][r] = f2bf(pv);
      }
#pragma unroll
    for (int off = 1; off < 16; off <<= 1)
#pragma unroll
      for (int r = 0; r < 4; ++r) psum[r] += __shfl_xor(psum[r], off, 64);
#pragma unroll
    for (int r = 0; r < 4; ++r) l_r[r] += psum[r];

    // P (C-layout) -> wave-private LDS -> two A-frags (16x64 tile)
#pragma unroll
    for (int sf = 0; sf < 4; ++sf)
#pragma unroll
      for (int r = 0; r < 4; ++r) pw[(fq * 4 + r) * 72 + sf * 16 + fr] = pb[sf][r];
    asm volatile("s_waitcnt lgkmcnt(0)" ::: "memory");
    const vbf8 pf0 = *(const vbf8*)(pw + fr * 72 + fq * 8);
    const vbf8 pf1 = *(const vbf8*)(pw + fr * 72 + 32 + fq * 8);

    // PV chunk A: 8 MFMAs from prefetched V regs
    __builtin_amdgcn_s_setprio(1);
#pragma unroll
    for (int df = 0; df < 8; ++df)
      oacc[df] = __builtin_amdgcn_mfma_f32_16x16x32_bf16(pf0, vreg[df], oacc[df], 0, 0, 0);
    __builtin_amdgcn_s_setprio(0);
    __builtin_amdgcn_sched_barrier(0);  // keep chunk-B loads below (reg reuse of vreg)

    // PV chunk B: reload vreg with the second 32-s chunk, 8 MFMAs
#pragma unroll
    for (int df = 0; df < 8; ++df) vreg[df] = *(const vbf8*)(vfp + df * 32768 + 512);
    __builtin_amdgcn_s_setprio(1);
#pragma unroll
    for (int df = 0; df < 8; ++df)
      oacc[df] = __builtin_amdgcn_mfma_f32_16x16x32_bf16(pf1, vreg[df], oacc[df], 0, 0, 0);
    __builtin_amdgcn_s_setprio(0);

    khp += 32768; klp += 32768; vfp += 4096;  // next 256-wide tile
  }

  // ---- 4-way s-quarter merge (only barriers in the kernel) ----
  __syncthreads();
  float* O_d = (float*)smem;                 // [3][16][128]
  float* m_s = (float*)(smem + 24576);       // [4][16]
  float* l_s = (float*)(smem + 24832);       // [4][16]
  if (sq > 0) {
#pragma unroll
    for (int i = 0; i < 8; ++i)
#pragma unroll
      for (int r = 0; r < 4; ++r)
        O_d[((sq - 1) * 16 + fq * 4 + r) * 128 + i * 16 + fr] = oacc[i][r];
  }
  if (fr == 0) {
#pragma unroll
    for (int r = 0; r < 4; ++r) {
      m_s[sq * 16 + fq * 4 + r] = m_r[r];
      l_s[sq * 16 + fq * 4 + r] = l_r[r];
    }
  }
  __syncthreads();
  if (sq == 0) {
#pragma unroll
    for (int r = 0; r < 4; ++r) {
      const int row = fq * 4 + r;
      float mv[4];
      float M = -__builtin_inff();
#pragma unroll
      for (int p = 0; p < 4; ++p) {
        mv[p] = m_s[p * 16 + row];
        M = fmaxf(M, mv[p]);
      }
      float wgt[4], denom = 0.f;
#pragma unroll
      for (int p = 0; p < 4; ++p) {
        wgt[p] = EXP2F(mv[p] - M);             // -inf (idle/masked quarter) -> 0
        denom += wgt[p] * l_s[p * 16 + row];
      }
      const float inv = 1.f / denom;           // sq0 always has the diagonal -> denom>0
#pragma unroll
      for (int i = 0; i < 8; ++i) {
        float o = wgt[0] * oacc[i][r];
#pragma unroll
        for (int p = 1; p < 4; ++p)
          o += wgt[p] * O_d[((p - 1) * 16 + row) * 128 + i * 16 + fr];
        out[(size_t)(bb * 2048 + q0g + row) * 128 + i * 16 + fr] = o * inv;
      }
    }
  }
}

// ---------------- host ----------------------------------------------------------------
extern "C" void kernel_launch(void* const* d_in, const int* in_sizes, int n_in, void* d_out,
                              int out_size, void* d_ws, size_t ws_size, hipStream_t stream) {
  const float* x = (const float*)d_in[0];
  const float* wq = (const float*)d_in[1];
  const float* wk = (const float*)d_in[2];
  const float* wv = (const float*)d_in[3];
  char* ws = (char*)d_ws;
  U16* wth = (U16*)(ws);              // 768 KB
  U16* wtl = (U16*)(ws + 786432);     // 768 KB
  U16* qfh = (U16*)(ws + 1572864);    // 4 MiB each below (fragment-major)
  U16* qfl = (U16*)(ws + 5767168);
  U16* kfh = (U16*)(ws + 9961472);
  U16* kfl = (U16*)(ws + 14155776);
  U16* vfr = (U16*)(ws + 18350080);
  float* out = (float*)d_out;

  wsplit_kernel<<<dim3(1536), dim3(256), 0, stream>>>(wq, wk, wv, wth, wtl);
  qkv_kernel<<<dim3(256, 3), dim3(256), 0, stream>>>(x, wth, wtl, qfh, qfl, kfh, kfl, vfr);
  flash_kernel<<<dim3(1024), dim3(256), 0, stream>>>(qfh, qfl, kfh, kfl, vfr, out);
}